// Round 1
// baseline (1365.702 us; speedup 1.0000x reference)
//
#include <hip/hip_runtime.h>
#include <cstdint>
#include <cstddef>

// ---------- types ----------
typedef __bf16 bf16x8 __attribute__((ext_vector_type(8)));
typedef float  f32x4  __attribute__((ext_vector_type(4)));

__device__ __forceinline__ unsigned short f2bf(float x) {
    unsigned int u = __builtin_bit_cast(unsigned int, x);
    u += 0x7fffu + ((u >> 16) & 1u);        // round-to-nearest-even
    return (unsigned short)(u >> 16);
}

// ---------- pass 1: f32 -> bf16 (X), rint+bf16 (W_ampa, W_shunt) ----------
// X: 8,388,608 f32 (2,097,152 float4) ; each W: 4,194,304 f32 (1,048,576 float4)
__global__ void convert_all(const float4* __restrict__ X,
                            const float4* __restrict__ Wa,
                            const float4* __restrict__ Ws,
                            ushort4* __restrict__ Xb,
                            ushort4* __restrict__ Wab,
                            ushort4* __restrict__ Wsb) {
    int i = blockIdx.x * 256 + threadIdx.x;     // 16384 * 256 = 4,194,304 units exactly
    if (i < 2097152) {
        float4 v = X[i];
        Xb[i] = make_ushort4(f2bf(v.x), f2bf(v.y), f2bf(v.z), f2bf(v.w));
    } else if (i < 3145728) {
        int t = i - 2097152;
        float4 v = Wa[t];
        Wab[t] = make_ushort4(f2bf(rintf(v.x)), f2bf(rintf(v.y)),
                              f2bf(rintf(v.z)), f2bf(rintf(v.w)));
    } else {
        int t = i - 3145728;
        float4 v = Ws[t];
        Wsb[t] = make_ushort4(f2bf(rintf(v.x)), f2bf(rintf(v.y)),
                              f2bf(rintf(v.z)), f2bf(rintf(v.w)));
    }
}

// ---------- pass 2: fused dual-GEMM + DPI neuron update ----------
// C_a[b][j] = sum_k X[b][k] * Wa[j][k], C_s likewise; then pointwise neuron model.
// Tile 128x128, BK=64, 256 threads = 4 waves (2x2), each wave 64x64 per output.
// LDS: 3 tiles [128][64] bf16 (A, Ba, Bs) = 48 KB, single-buffered.
// Staging via global_load_lds dwordx4; XOR chunk swizzle (chunk ^= row&7) applied
// on the GLOBAL source address and on the ds_read side (LDS dest stays linear).

constexpr int NCOL     = 2048;          // K == N == 2048
constexpr int ROWBYTES = NCOL * 2;      // bf16 row stride = 4096 B

__global__ __launch_bounds__(256, 2) void dpi_fused(
    const unsigned short* __restrict__ Xb,
    const unsigned short* __restrict__ Wab,
    const unsigned short* __restrict__ Wsb,
    const float* __restrict__ pIwA, const float* __restrict__ pIwS,
    const float* __restrict__ Imem_in, const float* __restrict__ Iampa_in,
    const float* __restrict__ Ishunt_in, const float* __restrict__ refr_in,
    float* __restrict__ out)
{
    __shared__ __align__(16) unsigned short lds[3 * 128 * 64];   // 48 KB
    unsigned short* As  = lds;
    unsigned short* Bas = lds + 8192;
    unsigned short* Bss = lds + 16384;

    const int tid  = threadIdx.x;
    const int lane = tid & 63;
    const int wid  = tid >> 6;
    const int wr   = wid >> 1;     // wave row (0..1) -> 64 rows
    const int wc   = wid & 1;      // wave col (0..1) -> 64 cols
    const int bn   = blockIdx.x;   // 0..15  (N tiles)
    const int bm   = blockIdx.y;   // 0..31  (M tiles)

    // --- staging setup: tile = 16 segments of 1 KB; seg = q*4 + wid ---
    int offq[4];
    const char* srcA[4];
    const char* srcBa[4];
    const char* srcBs[4];
#pragma unroll
    for (int q = 0; q < 4; ++q) {
        int off = (q * 4 + wid) * 1024 + lane * 16;   // byte offset in tile (linear dest)
        int row = off >> 7;                            // 128 B per row (BK=64 bf16)
        int cG  = ((off >> 4) & 7) ^ (row & 7);        // swizzled global chunk
        offq[q]  = off;
        srcA[q]  = (const char*)Xb  + (size_t)(bm * 128 + row) * ROWBYTES + cG * 16;
        srcBa[q] = (const char*)Wab + (size_t)(bn * 128 + row) * ROWBYTES + cG * 16;
        srcBs[q] = (const char*)Wsb + (size_t)(bn * 128 + row) * ROWBYTES + cG * 16;
    }

    // --- fragment LDS byte offsets (ds_read_b128, swizzle-matched) ---
    int offA[2][4], offB[2][4];
#pragma unroll
    for (int kk = 0; kk < 2; ++kk) {
#pragma unroll
        for (int m = 0; m < 4; ++m) {
            int c  = kk * 4 + (lane >> 4);             // logical 16B chunk (k/8)
            int cs = (c ^ (lane & 7)) * 16;            // row&7 == lane&7 for our rows
            offA[kk][m] = (wr * 64 + m * 16 + (lane & 15)) * 128 + cs;
            offB[kk][m] = (wc * 64 + m * 16 + (lane & 15)) * 128 + cs;
        }
    }

    f32x4 accA[4][4] = {};
    f32x4 accS[4][4] = {};

    const char* Ab  = (const char*)As;
    const char* Bab = (const char*)Bas;
    const char* Bsb = (const char*)Bss;

    for (int kt = 0; kt < 32; ++kt) {
        if (kt) __syncthreads();                       // previous tile fully consumed
#pragma unroll
        for (int q = 0; q < 4; ++q) {
            __builtin_amdgcn_global_load_lds(
                (__attribute__((address_space(1))) void*)(srcA[q] + kt * 128),
                (__attribute__((address_space(3))) void*)((char*)As + offq[q]), 16, 0, 0);
            __builtin_amdgcn_global_load_lds(
                (__attribute__((address_space(1))) void*)(srcBa[q] + kt * 128),
                (__attribute__((address_space(3))) void*)((char*)Bas + offq[q]), 16, 0, 0);
            __builtin_amdgcn_global_load_lds(
                (__attribute__((address_space(1))) void*)(srcBs[q] + kt * 128),
                (__attribute__((address_space(3))) void*)((char*)Bss + offq[q]), 16, 0, 0);
        }
        asm volatile("s_waitcnt vmcnt(0)" ::: "memory");
        __syncthreads();                               // tile visible to all waves

#pragma unroll
        for (int kk = 0; kk < 2; ++kk) {
            bf16x8 a[4], ba[4], bs[4];
#pragma unroll
            for (int m = 0; m < 4; ++m) {
                a[m]  = *(const bf16x8*)(Ab  + offA[kk][m]);
                ba[m] = *(const bf16x8*)(Bab + offB[kk][m]);
                bs[m] = *(const bf16x8*)(Bsb + offB[kk][m]);
            }
#pragma unroll
            for (int m = 0; m < 4; ++m) {
#pragma unroll
                for (int n = 0; n < 4; ++n) {
                    accA[m][n] = __builtin_amdgcn_mfma_f32_16x16x32_bf16(a[m], ba[n], accA[m][n], 0, 0, 0);
                    accS[m][n] = __builtin_amdgcn_mfma_f32_16x16x32_bf16(a[m], bs[n], accS[m][n], 0, 0, 0);
                }
            }
        }
    }

    // ---------- fused epilogue: DPI neuron update ----------
    const float IwA = pIwA[0];
    const float IwS = pIwS[0];

    constexpr float I0f       = 5e-14f;
    constexpr float c_Itau    = 1e-12f;    // Itau_mem
    constexpr float c_Igain   = 1e-12f;    // Igain_mem
    constexpr float c_Idc     = 1e-12f;
    constexpr float c_Ith     = 1e-12f;
    constexpr float c_pfb_th  = 1e-12f;
    constexpr float c_pfb_nrm = 1e-12f;
    constexpr float c_dt      = 1e-3f;
    constexpr float c_beta    = 0.05f;                       // I0/Itau_mem
    const float c_tau_mem  = (float)(0.025 / 0.705 * 3.0);   // Ut/kappa * Cmem/Itau
    const float c_tau_syn  = (float)(0.025 / 0.705 * 2.0);   // tau_ampa == tau_shunt
    const float c_p2       = (float)(0.705 / 1.705);         // kappa/(kappa+1)
    const float c0         = __powf(I0f, (float)(1.0 / 1.705));

    float* o_spk = out;
    float* o_mem = out + (size_t)8388608;
    float* o_amp = out + (size_t)16777216;
    float* o_shn = out + (size_t)25165824;
    float* o_ref = out + (size_t)33554432;

#pragma unroll
    for (int m = 0; m < 4; ++m) {
#pragma unroll
        for (int n = 0; n < 4; ++n) {
#pragma unroll
            for (int r = 0; r < 4; ++r) {
                int b = bm * 128 + wr * 64 + m * 16 + (lane >> 4) * 4 + r;  // C row
                int j = bn * 128 + wc * 64 + n * 16 + (lane & 15);          // C col
                size_t idx = (size_t)b * NCOL + j;

                float nA = accA[m][n][r];
                float nS = accS[m][n][r];
                float Im = Imem_in[idx];
                float Ia = Iampa_in[idx];
                float Is = Ishunt_in[idx];
                float rf = refr_in[idx];

                float dIa = -Ia / c_tau_syn;
                float Ia1 = fmaf(IwA, nA, Ia);          // gain ratio == 1
                float dIs = -Is / c_tau_syn;
                float Is1 = fmaf(IwS, nS, Is);

                float Iin = c_Idc + Ia1 + I0f - Is1;    // Inmda == I0
                Iin = (rf <= 0.0f) ? Iin : 0.0f;
                Iin = fmaxf(Iin, I0f);

                float sg  = 1.0f + __expf(-c_pfb_nrm * (Im - c_pfb_th));
                float Ifb = c0 * __powf(Im, c_p2) / sg;
                float fim = Ifb / c_Itau * (Im + c_Igain);

                float num = (Iin - c_Itau - I0f) - Im - c_beta * Im + fim;  // Iahp==I0
                float den = c_tau_mem * (1.0f + c_Igain / Im);
                float Im1 = fmaxf(fmaf(num / den, c_dt, Im), I0f);
                float IaO = fmaxf(fmaf(dIa, c_dt, Ia1), I0f);
                float IsO = fmaxf(fmaf(dIs, c_dt, Is1), I0f);
                float spk = (Im1 - c_Ith > 0.0f) ? 1.0f : 0.0f;
                float ImO = (spk > 0.0f) ? I0f : Im1;
                float rf1 = fmaxf(rf - c_dt, 0.0f);
                float rfO = (spk > 0.0f) ? 0.0f : rf1;   // refP == 0

                o_spk[idx] = spk;
                o_mem[idx] = ImO;
                o_amp[idx] = IaO;
                o_shn[idx] = IsO;
                o_ref[idx] = rfO;
            }
        }
    }
}

extern "C" void kernel_launch(void* const* d_in, const int* in_sizes, int n_in,
                              void* d_out, int out_size, void* d_ws, size_t ws_size,
                              hipStream_t stream) {
    const float* X    = (const float*)d_in[0];   // [4096,2048]
    const float* Wa   = (const float*)d_in[1];   // [2048,2048]
    const float* Ws   = (const float*)d_in[2];   // [2048,2048]
    const float* IwA  = (const float*)d_in[3];   // scalar
    const float* IwS  = (const float*)d_in[4];   // scalar
    const float* Imem = (const float*)d_in[5];
    const float* Iamp = (const float*)d_in[6];
    const float* Ishn = (const float*)d_in[7];
    const float* refr = (const float*)d_in[8];

    unsigned short* Xb  = (unsigned short*)d_ws;            // 16.78 MB
    unsigned short* Wab = Xb + (size_t)4096 * 2048;         //  8.39 MB
    unsigned short* Wsb = Wab + (size_t)2048 * 2048;        //  8.39 MB (total 33.6 MB)

    convert_all<<<16384, 256, 0, stream>>>((const float4*)X, (const float4*)Wa,
                                           (const float4*)Ws, (ushort4*)Xb,
                                           (ushort4*)Wab, (ushort4*)Wsb);

    dim3 grid(16, 32);   // (N/128, M/128)
    dpi_fused<<<grid, 256, 0, stream>>>(Xb, Wab, Wsb, IwA, IwS,
                                        Imem, Iamp, Ishn, refr, (float*)d_out);
}

// Round 2
// 180.168 us; speedup vs baseline: 7.5802x; 7.5802x over previous
//
#include <hip/hip_runtime.h>
#include <cstdint>
#include <cstddef>

// ---------- types ----------
typedef __bf16 bf16x8 __attribute__((ext_vector_type(8)));
typedef float  f32x4  __attribute__((ext_vector_type(4)));

__device__ __forceinline__ unsigned short f2bf(float x) {
    unsigned int u = __builtin_bit_cast(unsigned int, x);
    u += 0x7fffu + ((u >> 16) & 1u);        // round-to-nearest-even
    return (unsigned short)(u >> 16);
}

// ---------- pass 1: f32 -> bf16 (X), rint+bf16 (W_ampa, W_shunt) ----------
__global__ void convert_all(const float4* __restrict__ X,
                            const float4* __restrict__ Wa,
                            const float4* __restrict__ Ws,
                            ushort4* __restrict__ Xb,
                            ushort4* __restrict__ Wab,
                            ushort4* __restrict__ Wsb) {
    int i = blockIdx.x * 256 + threadIdx.x;     // 16384 * 256 = 4,194,304 units exactly
    if (i < 2097152) {
        float4 v = X[i];
        Xb[i] = make_ushort4(f2bf(v.x), f2bf(v.y), f2bf(v.z), f2bf(v.w));
    } else if (i < 3145728) {
        int t = i - 2097152;
        float4 v = Wa[t];
        Wab[t] = make_ushort4(f2bf(rintf(v.x)), f2bf(rintf(v.y)),
                              f2bf(rintf(v.z)), f2bf(rintf(v.w)));
    } else {
        int t = i - 3145728;
        float4 v = Ws[t];
        Wsb[t] = make_ushort4(f2bf(rintf(v.x)), f2bf(rintf(v.y)),
                              f2bf(rintf(v.z)), f2bf(rintf(v.w)));
    }
}

// ---------- pass 2: fused dual-GEMM + DPI neuron update ----------
// Tile BM=128 x BN=64, BK=64; 256 threads = 4 waves (2x2);
// wave (wr,wc) owns rows wr*64.., cols wc*32.. of BOTH output matrices.
// Per-thread acc: 2 x f32x4[4][2] = 64 regs (spill fix vs R1's 128).
// LDS: A[128][64] + Ba[64][64] + Bs[64][64] bf16 = 32 KB, single-buffered.
// XOR chunk swizzle (chunk ^= row&7) on global source + ds_read side; LDS linear.

constexpr int NCOL     = 2048;          // K == N == 2048
constexpr int ROWBYTES = NCOL * 2;      // bf16 row stride = 4096 B

__global__ __launch_bounds__(256) void dpi_fused(
    const unsigned short* __restrict__ Xb,
    const unsigned short* __restrict__ Wab,
    const unsigned short* __restrict__ Wsb,
    const float* __restrict__ pIwA, const float* __restrict__ pIwS,
    const float* __restrict__ Imem_in, const float* __restrict__ Iampa_in,
    const float* __restrict__ Ishunt_in, const float* __restrict__ refr_in,
    float* __restrict__ out)
{
    __shared__ __align__(16) unsigned short lds[(128 + 64 + 64) * 64];   // 32 KB
    unsigned short* As  = lds;               // [128][64]
    unsigned short* Bas = lds + 128 * 64;    // [64][64]
    unsigned short* Bss = lds + 192 * 64;    // [64][64]

    const int tid  = threadIdx.x;
    const int lane = tid & 63;
    const int wid  = tid >> 6;
    const int wr   = wid >> 1;     // wave row (0..1) -> 64 rows
    const int wc   = wid & 1;      // wave col (0..1) -> 32 cols
    const int bn   = blockIdx.x;   // 0..31  (N tiles of 64)
    const int bm   = blockIdx.y;   // 0..31  (M tiles of 128)

    // --- staging: A = 16 KB (16 x 1KB segs), B = 8 KB (8 segs) each ---
    int offqA[4];           const char* srcA[4];
    int offqB[2];           const char* srcBa[2];   const char* srcBs[2];
#pragma unroll
    for (int q = 0; q < 4; ++q) {
        int off = (q * 4 + wid) * 1024 + lane * 16;   // linear LDS dest byte offset
        int row = off >> 7;                            // 128 B per row (BK=64 bf16)
        int cG  = ((off >> 4) & 7) ^ (row & 7);        // swizzled global chunk
        offqA[q] = off;
        srcA[q]  = (const char*)Xb + (size_t)(bm * 128 + row) * ROWBYTES + cG * 16;
    }
#pragma unroll
    for (int q = 0; q < 2; ++q) {
        int off = (q * 4 + wid) * 1024 + lane * 16;
        int row = off >> 7;                            // 0..63
        int cG  = ((off >> 4) & 7) ^ (row & 7);
        offqB[q]  = off;
        srcBa[q]  = (const char*)Wab + (size_t)(bn * 64 + row) * ROWBYTES + cG * 16;
        srcBs[q]  = (const char*)Wsb + (size_t)(bn * 64 + row) * ROWBYTES + cG * 16;
    }

    // --- fragment LDS byte offsets (ds_read_b128, swizzle-matched) ---
    int offA[2][4], offB[2][2];
#pragma unroll
    for (int kk = 0; kk < 2; ++kk) {
        int cs = ((kk * 4 + (lane >> 4)) ^ (lane & 7)) * 16;  // row&7 == lane&7 here
#pragma unroll
        for (int m = 0; m < 4; ++m)
            offA[kk][m] = (wr * 64 + m * 16 + (lane & 15)) * 128 + cs;
#pragma unroll
        for (int n = 0; n < 2; ++n)
            offB[kk][n] = (wc * 32 + n * 16 + (lane & 15)) * 128 + cs;
    }

    f32x4 accA[4][2] = {};
    f32x4 accS[4][2] = {};

    const char* Ab  = (const char*)As;
    const char* Bab = (const char*)Bas;
    const char* Bsb = (const char*)Bss;

    for (int kt = 0; kt < 32; ++kt) {
        if (kt) __syncthreads();                       // previous tile fully consumed
#pragma unroll
        for (int q = 0; q < 4; ++q) {
            __builtin_amdgcn_global_load_lds(
                (__attribute__((address_space(1))) void*)(srcA[q] + kt * 128),
                (__attribute__((address_space(3))) void*)((char*)As + offqA[q]), 16, 0, 0);
        }
#pragma unroll
        for (int q = 0; q < 2; ++q) {
            __builtin_amdgcn_global_load_lds(
                (__attribute__((address_space(1))) void*)(srcBa[q] + kt * 128),
                (__attribute__((address_space(3))) void*)((char*)Bas + offqB[q]), 16, 0, 0);
            __builtin_amdgcn_global_load_lds(
                (__attribute__((address_space(1))) void*)(srcBs[q] + kt * 128),
                (__attribute__((address_space(3))) void*)((char*)Bss + offqB[q]), 16, 0, 0);
        }
        asm volatile("s_waitcnt vmcnt(0)" ::: "memory");
        __syncthreads();                               // tile visible to all waves

#pragma unroll
        for (int kk = 0; kk < 2; ++kk) {
            bf16x8 a[4], ba[2], bs[2];
#pragma unroll
            for (int m = 0; m < 4; ++m)
                a[m]  = *(const bf16x8*)(Ab  + offA[kk][m]);
#pragma unroll
            for (int n = 0; n < 2; ++n) {
                ba[n] = *(const bf16x8*)(Bab + offB[kk][n]);
                bs[n] = *(const bf16x8*)(Bsb + offB[kk][n]);
            }
#pragma unroll
            for (int m = 0; m < 4; ++m) {
#pragma unroll
                for (int n = 0; n < 2; ++n) {
                    accA[m][n] = __builtin_amdgcn_mfma_f32_16x16x32_bf16(a[m], ba[n], accA[m][n], 0, 0, 0);
                    accS[m][n] = __builtin_amdgcn_mfma_f32_16x16x32_bf16(a[m], bs[n], accS[m][n], 0, 0, 0);
                }
            }
        }
    }

    // ---------- fused epilogue: DPI neuron update ----------
    const float IwA = pIwA[0];
    const float IwS = pIwS[0];

    constexpr float I0f       = 5e-14f;
    constexpr float c_Itau    = 1e-12f;    // Itau_mem
    constexpr float c_Igain   = 1e-12f;    // Igain_mem
    constexpr float c_Idc     = 1e-12f;
    constexpr float c_Ith     = 1e-12f;
    constexpr float c_pfb_th  = 1e-12f;
    constexpr float c_pfb_nrm = 1e-12f;
    constexpr float c_dt      = 1e-3f;
    constexpr float c_beta    = 0.05f;                       // I0/Itau_mem
    const float c_tau_mem  = (float)(0.025 / 0.705 * 3.0);   // Ut/kappa * Cmem/Itau
    const float c_tau_syn  = (float)(0.025 / 0.705 * 2.0);   // tau_ampa == tau_shunt
    const float c_p2       = (float)(0.705 / 1.705);         // kappa/(kappa+1)
    const float c0         = __powf(I0f, (float)(1.0 / 1.705));

    float* o_spk = out;
    float* o_mem = out + (size_t)8388608;
    float* o_amp = out + (size_t)16777216;
    float* o_shn = out + (size_t)25165824;
    float* o_ref = out + (size_t)33554432;

#pragma unroll
    for (int m = 0; m < 4; ++m) {
#pragma unroll
        for (int n = 0; n < 2; ++n) {
#pragma unroll
            for (int r = 0; r < 4; ++r) {
                int b = bm * 128 + wr * 64 + m * 16 + (lane >> 4) * 4 + r;  // C row
                int j = bn * 64 + wc * 32 + n * 16 + (lane & 15);           // C col
                size_t idx = (size_t)b * NCOL + j;

                float nA = accA[m][n][r];
                float nS = accS[m][n][r];
                float Im = Imem_in[idx];
                float Ia = Iampa_in[idx];
                float Is = Ishunt_in[idx];
                float rf = refr_in[idx];

                float dIa = -Ia / c_tau_syn;
                float Ia1 = fmaf(IwA, nA, Ia);          // gain ratio == 1
                float dIs = -Is / c_tau_syn;
                float Is1 = fmaf(IwS, nS, Is);

                float Iin = c_Idc + Ia1 + I0f - Is1;    // Inmda == I0
                Iin = (rf <= 0.0f) ? Iin : 0.0f;
                Iin = fmaxf(Iin, I0f);

                float sg  = 1.0f + __expf(-c_pfb_nrm * (Im - c_pfb_th));
                float Ifb = c0 * __powf(Im, c_p2) / sg;
                float fim = Ifb / c_Itau * (Im + c_Igain);

                float num = (Iin - c_Itau - I0f) - Im - c_beta * Im + fim;  // Iahp==I0
                float den = c_tau_mem * (1.0f + c_Igain / Im);
                float Im1 = fmaxf(fmaf(num / den, c_dt, Im), I0f);
                float IaO = fmaxf(fmaf(dIa, c_dt, Ia1), I0f);
                float IsO = fmaxf(fmaf(dIs, c_dt, Is1), I0f);
                float spk = (Im1 - c_Ith > 0.0f) ? 1.0f : 0.0f;
                float ImO = (spk > 0.0f) ? I0f : Im1;
                float rf1 = fmaxf(rf - c_dt, 0.0f);
                float rfO = (spk > 0.0f) ? 0.0f : rf1;   // refP == 0

                o_spk[idx] = spk;
                o_mem[idx] = ImO;
                o_amp[idx] = IaO;
                o_shn[idx] = IsO;
                o_ref[idx] = rfO;
            }
        }
    }
}

extern "C" void kernel_launch(void* const* d_in, const int* in_sizes, int n_in,
                              void* d_out, int out_size, void* d_ws, size_t ws_size,
                              hipStream_t stream) {
    const float* X    = (const float*)d_in[0];   // [4096,2048]
    const float* Wa   = (const float*)d_in[1];   // [2048,2048]
    const float* Ws   = (const float*)d_in[2];   // [2048,2048]
    const float* IwA  = (const float*)d_in[3];   // scalar
    const float* IwS  = (const float*)d_in[4];   // scalar
    const float* Imem = (const float*)d_in[5];
    const float* Iamp = (const float*)d_in[6];
    const float* Ishn = (const float*)d_in[7];
    const float* refr = (const float*)d_in[8];

    unsigned short* Xb  = (unsigned short*)d_ws;            // 16.78 MB
    unsigned short* Wab = Xb + (size_t)4096 * 2048;         //  8.39 MB
    unsigned short* Wsb = Wab + (size_t)2048 * 2048;        //  8.39 MB (total 33.6 MB)

    convert_all<<<16384, 256, 0, stream>>>((const float4*)X, (const float4*)Wa,
                                           (const float4*)Ws, (ushort4*)Xb,
                                           (ushort4*)Wab, (ushort4*)Wsb);

    dim3 grid(32, 32);   // (N/64, M/128)
    dpi_fused<<<grid, 256, 0, stream>>>(Xb, Wab, Wsb, IwA, IwS,
                                        Imem, Iamp, Ishn, refr, (float*)d_out);
}